// Round 1
// baseline (167.789 us; speedup 1.0000x reference)
//
#include <hip/hip_runtime.h>
#include <stdint.h>

#define NCLS 21
#define BLK 256
#define APT 2
#define SPAN (BLK * APT)                       // 512 anchors per block
#define CLS_ROW_BYTES (NCLS * 4)               // 84 B per anchor row
#define CLS_TILE_BYTES (SPAN * CLS_ROW_BYTES)  // 43008 B staged per block
#define NCHUNK (CLS_TILE_BYTES / 1024)         // 42 x 1 KiB wave-chunks

// address-space types for global_load_lds (async global->LDS DMA)
typedef __attribute__((address_space(3))) void       lds_void_t;
typedef __attribute__((address_space(1))) const void gbl_void_t;

__device__ __forceinline__ float fmax4(const float4& v) {
    return fmaxf(fmaxf(v.x, v.y), fmaxf(v.z, v.w));
}
__device__ __forceinline__ float4 fmax44(const float4& a, const float4& b) {
    return make_float4(fmaxf(a.x, b.x), fmaxf(a.y, b.y),
                       fmaxf(a.z, b.z), fmaxf(a.w, b.w));
}

// Focal term, pure registers; row[t] extraction fused as compare-select
// (NO arrays -> NO scratch; dynamic-indexed arrays cost 3x here, R5).
// Arithmetic order identical to previous verified kernel (absmax 0.0).
__device__ __forceinline__ float focal_regs(
    int t, const float4& c0, const float4& c1, const float4& c2,
    const float4& c3, const float4& c4, float c20)
{
    float m = fmaxf(fmax4(fmax44(fmax44(c0, c1), fmax44(c2, c3))),
                    fmaxf(fmax4(c4), c20));
    float s = 0.0f, et = 0.0f;
#define FSTEP(val, idx) { float e = __expf((val) - m); s += e; et = (t == (idx)) ? e : et; }
    FSTEP(c0.x, 0)  FSTEP(c0.y, 1)  FSTEP(c0.z, 2)  FSTEP(c0.w, 3)
    FSTEP(c1.x, 4)  FSTEP(c1.y, 5)  FSTEP(c1.z, 6)  FSTEP(c1.w, 7)
    FSTEP(c2.x, 8)  FSTEP(c2.y, 9)  FSTEP(c2.z, 10) FSTEP(c2.w, 11)
    FSTEP(c3.x, 12) FSTEP(c3.y, 13) FSTEP(c3.z, 14) FSTEP(c3.w, 15)
    FSTEP(c4.x, 16) FSTEP(c4.y, 17) FSTEP(c4.z, 18) FSTEP(c4.w, 19)
    FSTEP(c20,  20)
#undef FSTEP
    float pt = et / s;
    pt = fminf(fmaxf(pt, 1e-7f), 1.0f - 1e-7f);
    float om = 1.0f - pt;
    return -__logf(pt) * om * om;
}

// Read one anchor row from LDS (21 x ds_read, 84 B stride across lanes
// -> banks (21*lane+k)%32, gcd(21,32)=1 -> exactly 2 lanes/bank = free).
__device__ __forceinline__ float focal_lds(int t, const float* __restrict__ row)
{
    float4 c0  = make_float4(row[0],  row[1],  row[2],  row[3]);
    float4 c1  = make_float4(row[4],  row[5],  row[6],  row[7]);
    float4 c2  = make_float4(row[8],  row[9],  row[10], row[11]);
    float4 c3  = make_float4(row[12], row[13], row[14], row[15]);
    float4 c4  = make_float4(row[16], row[17], row[18], row[19]);
    float  c20 = row[20];
    return focal_regs(t, c0, c1, c2, c3, c4, c20);
}

__device__ __forceinline__ float smooth_l1(const float4& lp, const float4& lt) {
    float d0 = lp.x - lt.x, d1 = lp.y - lt.y, d2 = lp.z - lt.z, d3 = lp.w - lt.w;
    float a0 = fabsf(d0), a1 = fabsf(d1), a2 = fabsf(d2), a3 = fabsf(d3);
    float s = 0.0f;
    s += (a0 < 1.0f) ? 0.5f * d0 * d0 : a0 - 0.5f;
    s += (a1 < 1.0f) ? 0.5f * d1 * d1 : a1 - 0.5f;
    s += (a2 < 1.0f) ? 0.5f * d2 * d2 : a2 - 0.5f;
    s += (a3 < 1.0f) ? 0.5f * d3 * d3 : a3 - 0.5f;
    return s;
}

// Two-kernel structure: per-block float2 partial + tiny reduce dispatch.
// Single-kernel last-block-done finalize costs +50..+100 us on gfx950
// (same-line agent-scope RMW serialization; measured R5/R8/R9).
//
// cls_preds is staged coalesced into LDS via global_load_lds width=16:
// 1 KiB contiguous per wave-instruction, vs the old per-thread 84 B-stride
// row loads where each dwordx4 touched ~42-64 cache lines (split, unaligned).
__global__ __launch_bounds__(BLK) void focal_main(
    const float* __restrict__ loc_p,
    const float* __restrict__ loc_t,
    const float* __restrict__ cls_p,
    const int*   __restrict__ cls_t,
    float2* __restrict__ partials,
    int n_anchors)
{
    __shared__ float cls_s[SPAN * NCLS];   // 43008 B -> 3 blocks/CU
    __shared__ float redL[4], redP[4];

    const int tid  = threadIdx.x;
    const int wave = tid >> 6;
    const int lane = tid & 63;
    const long long blk0       = (long long)blockIdx.x * SPAN;
    const long long base_byte  = blk0 * CLS_ROW_BYTES;
    const long long total_byte = (long long)n_anchors * CLS_ROW_BYTES;

    // ---- async coalesced staging: 16 B/lane, linear LDS dest (wave-uniform
    //      base + lane*16 — matches HW semantics, m104/m108) ----
    {
        const char* g = (const char*)cls_p + base_byte + (long long)lane * 16;
        char*       l = (char*)cls_s;
        for (int c = wave; c < NCHUNK; c += BLK / 64) {
            const long long gb = base_byte + (long long)c * 1024 + lane * 16;
            if (gb + 16 <= total_byte) {
                __builtin_amdgcn_global_load_lds(
                    (gbl_void_t*)(g + (long long)c * 1024),
                    (lds_void_t*)(l + c * 1024),
                    16, 0, 0);
            } else if (gb < total_byte) {
                // ragged tail (not hit at n=1,048,576): scalar copy
                for (long long b = gb; b < total_byte; b += 4)
                    cls_s[(b - base_byte) >> 2] = cls_p[b >> 2];
            }
        }
    }

    // ---- loc/cls_t loads (already perfectly coalesced) issued while the
    //      LDS staging is in flight ----
    const long long a0 = blk0 + tid;
    const long long a1 = a0 + BLK;
    const bool v0 = (a0 < n_anchors), v1 = (a1 < n_anchors);

    int t0 = -1, t1 = -1;
    float4 lp0, lt0, lp1, lt1;
    if (v0) {
        t0  = cls_t[a0];
        lp0 = ((const float4*)loc_p)[a0];
        lt0 = ((const float4*)loc_t)[a0];
    }
    if (v1) {
        t1  = cls_t[a1];
        lp1 = ((const float4*)loc_p)[a1];
        lt1 = ((const float4*)loc_t)[a1];
    }

    asm volatile("s_waitcnt vmcnt(0)" ::: "memory");  // staging drained
    __syncthreads();

    // ---- pure-register compute, rows read from LDS (2-way = conflict-free) ----
    float acc = 0.0f, npos = 0.0f;
    if (v0) {
        if (t0 > 0)  { acc += smooth_l1(lp0, lt0); npos += 1.0f; }
        if (t0 >= 0) acc += focal_lds(t0, cls_s + tid * NCLS);
    }
    if (v1) {
        if (t1 > 0)  { acc += smooth_l1(lp1, lt1); npos += 1.0f; }
        if (t1 >= 0) acc += focal_lds(t1, cls_s + (tid + BLK) * NCLS);
    }

    // ---- wave shuffle -> LDS -> one float2 per block ----
    #pragma unroll
    for (int off = 32; off > 0; off >>= 1) {
        acc  += __shfl_down(acc,  off, 64);
        npos += __shfl_down(npos, off, 64);
    }
    if (lane == 0) { redL[wave] = acc; redP[wave] = npos; }
    __syncthreads();
    if (tid == 0)
        partials[blockIdx.x] = make_float2(redL[0] + redL[1] + redL[2] + redL[3],
                                           redP[0] + redP[1] + redP[2] + redP[3]);
}

#define RBLK 1024
__global__ __launch_bounds__(RBLK) void focal_reduce(
    const float2* __restrict__ partials, float* __restrict__ out, int npart)
{
    __shared__ float red[32];
    float L = 0.0f, P = 0.0f;
    for (int i = threadIdx.x; i < npart; i += RBLK) {
        float2 v = partials[i];
        L += v.x; P += v.y;
    }
    #pragma unroll
    for (int off = 32; off > 0; off >>= 1) {
        L += __shfl_down(L, off, 64);
        P += __shfl_down(P, off, 64);
    }
    const int wave = threadIdx.x >> 6, lane = threadIdx.x & 63;
    if (lane == 0) { red[wave * 2] = L; red[wave * 2 + 1] = P; }
    __syncthreads();
    if (threadIdx.x == 0) {
        float Ls = 0.0f, Ps = 0.0f;
        #pragma unroll
        for (int w = 0; w < RBLK / 64; ++w) { Ls += red[w * 2]; Ps += red[w * 2 + 1]; }
        out[0] = Ls / Ps;
    }
}

extern "C" void kernel_launch(void* const* d_in, const int* in_sizes, int n_in,
                              void* d_out, int out_size, void* d_ws, size_t ws_size,
                              hipStream_t stream)
{
    const float* loc_p = (const float*)d_in[0];
    const float* loc_t = (const float*)d_in[1];
    const float* cls_p = (const float*)d_in[2];
    const int*   cls_t = (const int*)d_in[3];
    // d_in[4] (pos) ignored: pos == (cls_targets > 0) exactly.
    float*  out = (float*)d_out;
    float2* ws  = (float2*)d_ws;

    const int n_anchors = in_sizes[3];                  // B*A = 1,048,576
    const int blocks = (n_anchors + SPAN - 1) / SPAN;   // 2048

    focal_main<<<blocks, BLK, 0, stream>>>(loc_p, loc_t, cls_p, cls_t, ws, n_anchors);
    focal_reduce<<<1, RBLK, 0, stream>>>(ws, out, blocks);
}